// Round 7
// baseline (5542.992 us; speedup 1.0000x reference)
//
#include <hip/hip_runtime.h>
#include <math.h>

#define NN 50000
#define NE 800000
#define FD 128
#define EDD 32
#define NG 64
#define NA 16
#define EPSV 1e-5f
#define NCH 196            // ceil(NN/256) chunks for the scan
#define EC 32              // edges staged per chunk per wave
#define NPW 4              // nodes per body
#define BR 128             // node GEMM: rows per block tile
#define BK 32              // node GEMM: k panel

typedef float v2f __attribute__((ext_vector_type(2)));

__device__ __forceinline__ float sigf(float v) { return 1.0f / (1.0f + __expf(-v)); }
__device__ __forceinline__ v2f mk2(float a, float b) { v2f r; r.x = a; r.y = b; return r; }
__device__ __forceinline__ v2f pfma(v2f a, v2f b, v2f c) { return __builtin_elementwise_fma(a, b, c); }
__device__ __forceinline__ v2f pmax0(v2f a) { return __builtin_elementwise_max(a, mk2(0.f, 0.f)); }

// ============ counting sort of edges by dst (CSR build) ====================
__global__ __launch_bounds__(256) void count_kernel(const int* __restrict__ ei,
                                                    int* __restrict__ off)
{
    const int e = blockIdx.x * 256 + threadIdx.x;
    atomicAdd(&off[ei[NE + e]], 1);
}

__global__ __launch_bounds__(256) void scan1_kernel(const int* __restrict__ off,
                                                    int* __restrict__ chunk)
{
    __shared__ int red[256];
    const int i = blockIdx.x * 256 + threadIdx.x;
    red[threadIdx.x] = (i < NN) ? off[i] : 0;
    __syncthreads();
    for (int o = 128; o > 0; o >>= 1) {
        if (threadIdx.x < o) red[threadIdx.x] += red[threadIdx.x + o];
        __syncthreads();
    }
    if (threadIdx.x == 0) chunk[blockIdx.x] = red[0];
}

__global__ __launch_bounds__(256) void scan2_kernel(int* __restrict__ chunk)
{
    __shared__ int sh[256];
    const int t = threadIdx.x;
    const int v = (t < NCH) ? chunk[t] : 0;
    sh[t] = v;
    __syncthreads();
    for (int o = 1; o < 256; o <<= 1) {
        int x = (t >= o) ? sh[t - o] : 0;
        __syncthreads();
        sh[t] += x;
        __syncthreads();
    }
    if (t < NCH) chunk[t] = sh[t] - v;
}

__global__ __launch_bounds__(256) void scan3_kernel(int* __restrict__ off,
                                                    int* __restrict__ cur,
                                                    const int* __restrict__ chunk)
{
    __shared__ int sh[256];
    const int t = threadIdx.x;
    const int i = blockIdx.x * 256 + t;
    const int v = (i < NN) ? off[i] : 0;
    sh[t] = v;
    __syncthreads();
    for (int o = 1; o < 256; o <<= 1) {
        int x = (t >= o) ? sh[t - o] : 0;
        __syncthreads();
        sh[t] += x;
        __syncthreads();
    }
    const int ex = sh[t] - v + chunk[blockIdx.x];
    if (i < NN) { off[i] = ex; cur[i] = ex; }
    if (i == 0) off[NN] = NE;
}

__global__ __launch_bounds__(256) void scatter_kernel(const int* __restrict__ ei,
                                                      int* __restrict__ cur,
                                                      int2* __restrict__ perm)
{
    const int e = blockIdx.x * 256 + threadIdx.x;
    const int src = ei[e];
    const int dst = ei[NE + e];
    const int pos = atomicAdd(&cur[dst], 1);
    perm[pos] = make_int2(src, e);
}

// ============ gather edge stage: persistent waves + work stealing ==========
// R1 skeleton (proven demotion-free) with ONE change: edge attrs are no
// longer staged through LDS (was 8x ds_read_b128/edge = DS-pipe hog).
// Per edge, the 32 attrs load directly from eattr via 8 wave-uniform
// global dwordx4 (L2 broadcast, VMEM pipe) into 8 NAMED float4 locals
// (no arrays -> no scratch demotion). Only the int2 perm entries are
// LDS-staged per chunk (512 B).
template<bool TR>
__global__ __launch_bounds__(128) void edge_agg_kernel(
    const float* __restrict__ xin, const float* __restrict__ cs,
    const float* __restrict__ cq, const float* __restrict__ ga,
    const float* __restrict__ bb, const float* __restrict__ eattr,
    const int* __restrict__ off, const int2* __restrict__ perm,
    const float* __restrict__ We, const float* __restrict__ be,
    int* __restrict__ ctr, float* __restrict__ xpa)
{
    __shared__ int2 pe_s[2][EC];          // per-wave private, 512 B
    const int t = threadIdx.x;
    const int w = t >> 6;
    const int l = t & 63;

    // packed weights: wk[k] = {We[l][k], We[l+64][k]}
    v2f wk[EDD];
    {
        const float4* a  = (const float4*)(We + l * EDD);
        const float4* b2 = (const float4*)(We + (l + 64) * EDD);
#pragma unroll
        for (int i = 0; i < 8; ++i) {
            const float4 va = a[i], vb = b2[i];
            wk[4*i+0] = mk2(va.x, vb.x);
            wk[4*i+1] = mk2(va.y, vb.y);
            wk[4*i+2] = mk2(va.z, vb.z);
            wk[4*i+3] = mk2(va.w, vb.w);
        }
    }
    const v2f bev = mk2(be[l], be[l + 64]);
    v2f Av = mk2(1.f, 1.f), Bv = mk2(0.f, 0.f);
    if (TR) {
        const float invN = 1.0f / (float)NN;
        const float m0 = cs[l] * invN;
        const float i0 = rsqrtf(cq[l] * invN - m0 * m0 + EPSV);
        const float m1 = cs[l + 64] * invN;
        const float i1 = rsqrtf(cq[l + 64] * invN - m1 * m1 + EPSV);
        Av = mk2(i0 * ga[l], i1 * ga[l + 64]);
        Bv = mk2(bb[l] - m0 * Av.x, bb[l + 64] - m1 * Av.y);
    }

    auto ldx = [&](int node) -> v2f {
        v2f v = mk2(xin[(long)node * FD + l], xin[(long)node * FD + 64 + l]);
        return TR ? pmax0(pfma(v, Av, Bv)) : v;
    };

    for (;;) {
        int u = 0;
        if (l == 0) u = atomicAdd(ctr, 1);
        u = __builtin_amdgcn_readfirstlane(u);
        if (u >= NN / 8) break;
#pragma unroll 1
        for (int rep = 0; rep < 2; ++rep) {
            const int n0 = u * 8 + rep * NPW;
            const int o0 = off[n0];
            const int o1 = off[n0 + 1];
            const int o2 = off[n0 + 2];
            const int o3 = off[n0 + 3];
            const int o4 = off[n0 + 4];
            const v2f ni0 = ldx(n0), ni1 = ldx(n0 + 1);
            const v2f ni2 = ldx(n0 + 2), ni3 = ldx(n0 + 3);
            const int nchk = (o4 - o0 + EC - 1) / EC;

            int2 ppe = make_int2(0, 0);
            auto prefetch = [&](int ch) {
                const int bse = o0 + ch * EC;
                const int nn = min(EC, o4 - bse);
                if (l < EC && l < nn) ppe = perm[bse + l];
            };

            int cur = n0;
            int nxt_end = o1;
            v2f acc = ni0;
            int eidx = o0;

            if (nchk > 0) prefetch(0);
#pragma unroll 1
            for (int ch = 0; ch < nchk; ++ch) {
                if (l < EC) pe_s[w][l] = ppe;
                const int base = o0 + ch * EC;
                const int n = min(EC, o4 - base);
                if (ch + 1 < nchk) prefetch(ch + 1);

                auto edge = [&](int j, v2f cxv) {
                    while (eidx == nxt_end) {
                        xpa[(long)cur * FD + l]      = acc.x;
                        xpa[(long)cur * FD + 64 + l] = acc.y;
                        ++cur;
                        acc     = (cur == n0 + 1) ? ni1 : (cur == n0 + 2) ? ni2 : ni3;
                        nxt_end = (cur == n0 + 1) ? o2  : (cur == n0 + 2) ? o3  : o4;
                    }
                    // 32 attrs: 8 wave-uniform dwordx4 into NAMED locals
                    const int ey = pe_s[w][j].y;
                    const float4* ev = (const float4*)(eattr + (long)ey * EDD);
                    const float4 v0 = ev[0];
                    const float4 v1 = ev[1];
                    const float4 v2 = ev[2];
                    const float4 v3 = ev[3];
                    const float4 v4 = ev[4];
                    const float4 v5 = ev[5];
                    const float4 v6 = ev[6];
                    const float4 v7 = ev[7];
                    v2f ma = bev, mb = mk2(0.f, 0.f);
                    ma = pfma(mk2(v0.x, v0.x), wk[0],  ma);
                    mb = pfma(mk2(v0.y, v0.y), wk[1],  mb);
                    ma = pfma(mk2(v0.z, v0.z), wk[2],  ma);
                    mb = pfma(mk2(v0.w, v0.w), wk[3],  mb);
                    ma = pfma(mk2(v1.x, v1.x), wk[4],  ma);
                    mb = pfma(mk2(v1.y, v1.y), wk[5],  mb);
                    ma = pfma(mk2(v1.z, v1.z), wk[6],  ma);
                    mb = pfma(mk2(v1.w, v1.w), wk[7],  mb);
                    ma = pfma(mk2(v2.x, v2.x), wk[8],  ma);
                    mb = pfma(mk2(v2.y, v2.y), wk[9],  mb);
                    ma = pfma(mk2(v2.z, v2.z), wk[10], ma);
                    mb = pfma(mk2(v2.w, v2.w), wk[11], mb);
                    ma = pfma(mk2(v3.x, v3.x), wk[12], ma);
                    mb = pfma(mk2(v3.y, v3.y), wk[13], mb);
                    ma = pfma(mk2(v3.z, v3.z), wk[14], ma);
                    mb = pfma(mk2(v3.w, v3.w), wk[15], mb);
                    ma = pfma(mk2(v4.x, v4.x), wk[16], ma);
                    mb = pfma(mk2(v4.y, v4.y), wk[17], mb);
                    ma = pfma(mk2(v4.z, v4.z), wk[18], ma);
                    mb = pfma(mk2(v4.w, v4.w), wk[19], mb);
                    ma = pfma(mk2(v5.x, v5.x), wk[20], ma);
                    mb = pfma(mk2(v5.y, v5.y), wk[21], mb);
                    ma = pfma(mk2(v5.z, v5.z), wk[22], ma);
                    mb = pfma(mk2(v5.w, v5.w), wk[23], mb);
                    ma = pfma(mk2(v6.x, v6.x), wk[24], ma);
                    mb = pfma(mk2(v6.y, v6.y), wk[25], mb);
                    ma = pfma(mk2(v6.z, v6.z), wk[26], ma);
                    mb = pfma(mk2(v6.w, v6.w), wk[27], mb);
                    ma = pfma(mk2(v7.x, v7.x), wk[28], ma);
                    mb = pfma(mk2(v7.y, v7.y), wk[29], mb);
                    ma = pfma(mk2(v7.z, v7.z), wk[30], ma);
                    mb = pfma(mk2(v7.w, v7.w), wk[31], mb);
                    const v2f tx = TR ? pmax0(pfma(cxv, Av, Bv)) : cxv;
                    acc += pmax0(ma + mb + tx);
                    ++eidx;
                };

                v2f cx[4];
#pragma unroll
                for (int q = 0; q < 4; ++q) {
                    if (q < n) {
                        const int s = pe_s[w][q].x;
                        cx[q] = mk2(xin[(long)s * FD + l], xin[(long)s * FD + 64 + l]);
                    } else cx[q] = mk2(0.f, 0.f);
                }
                const int ng = (n + 3) >> 2;
                for (int g = 0; g < ng; ++g) {
                    const int jg = g * 4;
                    v2f nx[4];
#pragma unroll
                    for (int q = 0; q < 4; ++q) {
                        const int j = jg + 4 + q;
                        if (j < n) {
                            const int s = pe_s[w][j].x;
                            nx[q] = mk2(xin[(long)s * FD + l], xin[(long)s * FD + 64 + l]);
                        } else nx[q] = mk2(0.f, 0.f);
                    }
#pragma unroll
                    for (int q = 0; q < 4; ++q) {
                        const int j = jg + q;
                        if (j < n) edge(j, cx[q]);
                    }
#pragma unroll
                    for (int q = 0; q < 4; ++q) cx[q] = nx[q];
                }
            }
            for (;;) {
                xpa[(long)cur * FD + l]      = acc.x;
                xpa[(long)cur * FD + 64 + l] = acc.y;
                if (cur == n0 + 3) break;
                ++cur;
                acc = (cur == n0 + 1) ? ni1 : (cur == n0 + 2) ? ni2 : ni3;
            }
        }
    }
}

// ============ node GEMM: hpre = xpa @ W^T + b, fused BN column stats =======
__global__ __launch_bounds__(256) void node_kernel(
    const float* __restrict__ xpa, const float* __restrict__ W,
    const float* __restrict__ b, float* __restrict__ hpre,
    float* __restrict__ colsum, float* __restrict__ colsq)
{
    __shared__ float As[BK][BR + 4];
    __shared__ float Ws[BK][128 + 4];
    const int t = threadIdx.x;
    const int cg = t & 15;        // col group -> cols c0..c0+7
    const int rg = t >> 4;        // row group -> rows rg*8..+7
    const int c0 = cg * 8;
    const int r0 = blockIdx.x * BR;
    const int sr = t >> 1;        // staging row/col 0..127
    const int kq = (t & 1) * 16;  // staging k offset

    float acc[8][8];
#pragma unroll
    for (int j = 0; j < 8; ++j)
#pragma unroll
        for (int i = 0; i < 8; ++i) acc[j][i] = 0.f;

#pragma unroll 1
    for (int pn = 0; pn < 4; ++pn) {
        const int k0 = pn * BK;
        __syncthreads();
        {
            const int rG = r0 + sr;
            const float* ap = xpa + (long)rG * FD + k0 + kq;
#pragma unroll
            for (int i = 0; i < 4; ++i) {
                const float4 v = (rG < NN) ? *(const float4*)(ap + i * 4)
                                           : make_float4(0.f, 0.f, 0.f, 0.f);
                As[kq + i * 4 + 0][sr] = v.x;
                As[kq + i * 4 + 1][sr] = v.y;
                As[kq + i * 4 + 2][sr] = v.z;
                As[kq + i * 4 + 3][sr] = v.w;
            }
        }
        {
            const float* wp2 = W + sr * FD + k0 + kq;
#pragma unroll
            for (int i = 0; i < 4; ++i) {
                const float4 v = *(const float4*)(wp2 + i * 4);
                Ws[kq + i * 4 + 0][sr] = v.x;
                Ws[kq + i * 4 + 1][sr] = v.y;
                Ws[kq + i * 4 + 2][sr] = v.z;
                Ws[kq + i * 4 + 3][sr] = v.w;
            }
        }
        __syncthreads();
#pragma unroll
        for (int k = 0; k < BK; ++k) {
            const float4 a0 = *(const float4*)&As[k][rg * 8];
            const float4 a1 = *(const float4*)&As[k][rg * 8 + 4];
            const float4 w0 = *(const float4*)&Ws[k][c0];
            const float4 w1 = *(const float4*)&Ws[k][c0 + 4];
            const float av[8] = {a0.x,a0.y,a0.z,a0.w,a1.x,a1.y,a1.z,a1.w};
            const float wv[8] = {w0.x,w0.y,w0.z,w0.w,w1.x,w1.y,w1.z,w1.w};
#pragma unroll
            for (int j = 0; j < 8; ++j)
#pragma unroll
                for (int i = 0; i < 8; ++i)
                    acc[j][i] = fmaf(av[j], wv[i], acc[j][i]);
        }
    }
    float bv[8];
#pragma unroll
    for (int i = 0; i < 8; ++i) bv[i] = b[c0 + i];
    float s1[8], s2[8];
#pragma unroll
    for (int i = 0; i < 8; ++i) { s1[i] = 0.f; s2[i] = 0.f; }
#pragma unroll
    for (int j = 0; j < 8; ++j) {
        const int r = r0 + rg * 8 + j;
        if (r < NN) {
            float v[8];
#pragma unroll
            for (int i = 0; i < 8; ++i) {
                v[i] = acc[j][i] + bv[i];
                s1[i] += v[i];
                s2[i] += v[i] * v[i];
            }
            *(float4*)(hpre + (long)r * FD + c0)     = make_float4(v[0],v[1],v[2],v[3]);
            *(float4*)(hpre + (long)r * FD + c0 + 4) = make_float4(v[4],v[5],v[6],v[7]);
        }
    }
    __syncthreads();
#pragma unroll
    for (int i = 0; i < 8; ++i) As[rg][c0 + i] = s1[i];
    __syncthreads();
    if (t < 128) {
        float s = 0.f;
#pragma unroll
        for (int g = 0; g < 16; ++g) s += As[g][t];
        atomicAdd(&colsum[t], s);
    }
    __syncthreads();
#pragma unroll
    for (int i = 0; i < 8; ++i) As[rg][c0 + i] = s2[i];
    __syncthreads();
    if (t < 128) {
        float s = 0.f;
#pragma unroll
        for (int g = 0; g < 16; ++g) s += As[g][t];
        atomicAdd(&colsq[t], s);
    }
}

// ============ BN + relu + sigmoid + per-graph pooled sums (layer 2) ========
__global__ __launch_bounds__(256) void norm_pool_kernel(
    const float* __restrict__ hpre, const float* __restrict__ cs,
    const float* __restrict__ cq, const float* __restrict__ ga,
    const float* __restrict__ bb, const int* __restrict__ batch,
    float* __restrict__ pooled)
{
    __shared__ float pl[NG * FD];
    const int t = threadIdx.x;
    const int c = t & 127;
    const int half = t >> 7;
    const int r0 = blockIdx.x * 128;
    const int rend = min(r0 + 128, NN);
    const int gmin = batch[r0];
    const int gmax = batch[rend - 1];
    const int span = gmax - gmin + 1;
    for (int i = t; i < span * FD; i += 256) pl[i] = 0.f;
    __syncthreads();
    const float invN = 1.0f / (float)NN;
    const float m = cs[c] * invN;
    const float iv = rsqrtf(cq[c] * invN - m * m + EPSV);
    const float gg = ga[c];
    const float bt = bb[c];
    for (int ir = half; ir < 128; ir += 2) {
        const int r = r0 + ir;
        if (r >= rend) break;
        float v = (hpre[(long)r * FD + c] - m) * iv * gg + bt;
        v = sigf(fmaxf(v, 0.f));
        atomicAdd(&pl[(batch[r] - gmin) * FD + c], v);
    }
    __syncthreads();
    for (int i = t; i < span * FD; i += 256) atomicAdd(&pooled[gmin * FD + i], pl[i]);
}

__device__ __forceinline__ int lbound(const int* __restrict__ a, int n, int v)
{
    int lo = 0, hi = n;
    while (lo < hi) { const int mid = (lo + hi) >> 1; if (a[mid] < v) lo = mid + 1; else hi = mid; }
    return lo;
}

// ============ action MLP head, single block ================================
__global__ __launch_bounds__(256) void mlp_kernel(
    const float* __restrict__ pooled, const int* __restrict__ batch,
    const float* __restrict__ A1w, const float* __restrict__ A1b,
    const float* __restrict__ Ag1, const float* __restrict__ Ab1,
    const float* __restrict__ A2w, const float* __restrict__ A2b,
    const float* __restrict__ Ag2, const float* __restrict__ Ab2,
    const float* __restrict__ A3w, const float* __restrict__ A3b,
    float* __restrict__ out)
{
    __shared__ float Z[NG * FD];
    __shared__ float red[256];
    __shared__ float ml[128], il[128];
    __shared__ float cr[NG];
    const int t = threadIdx.x;
    const int c = t & 127;
    const int half = t >> 7;
    if (t < NG) {
        const int lo = lbound(batch, NN, t);
        const int hi = lbound(batch, NN, t + 1);
        cr[t] = 1.0f / fmaxf((float)(hi - lo), 1.0f);
    }
    float acc[32];
#pragma unroll
    for (int ii = 0; ii < 32; ++ii) acc[ii] = 0.f;
#pragma unroll 1
    for (int kc = 0; kc < 4; ++kc) {
        float4 wr[8];
        const float4* wp = (const float4*)(A1w + c * FD + kc * 32);
#pragma unroll
        for (int i = 0; i < 8; ++i) wr[i] = wp[i];
#pragma unroll
        for (int ii = 0; ii < 32; ++ii) {
            const int gi = half + 2 * ii;
            const float4* pp = (const float4*)(pooled + gi * FD + kc * 32);
            float d = 0.f;
#pragma unroll
            for (int i = 0; i < 8; ++i) {
                const float4 w4 = wr[i], p4 = pp[i];
                d += w4.x * p4.x + w4.y * p4.y + w4.z * p4.z + w4.w * p4.w;
            }
            acc[ii] += d;
        }
    }
    __syncthreads();
    float s1 = 0.f, s2 = 0.f;
    {
        const float bc = A1b[c];
#pragma unroll
        for (int ii = 0; ii < 32; ++ii) {
            const int gi = half + 2 * ii;
            const float a = fmaf(acc[ii], cr[gi], bc);
            acc[ii] = a; s1 += a; s2 += a * a;
        }
    }
    red[t] = s1; __syncthreads();
    if (t < 128) ml[c] = (red[t] + red[t + 128]) * (1.0f / NG);
    __syncthreads();
    red[t] = s2; __syncthreads();
    if (t < 128) {
        const float ms = (red[t] + red[t + 128]) * (1.0f / NG);
        const float mm = ml[c];
        il[c] = rsqrtf(ms - mm * mm + EPSV);
    }
    __syncthreads();
    {
        const float mm = ml[c], iv = il[c], gg = Ag1[c], bb = Ab1[c];
#pragma unroll
        for (int ii = 0; ii < 32; ++ii) {
            const int gi = half + 2 * ii;
            Z[gi * FD + c] = fmaxf((acc[ii] - mm) * iv * gg + bb, 0.f);
        }
    }
    __syncthreads();
#pragma unroll
    for (int ii = 0; ii < 32; ++ii) acc[ii] = 0.f;
#pragma unroll 1
    for (int kc = 0; kc < 4; ++kc) {
        float4 wr[8];
        const float4* wp = (const float4*)(A2w + c * FD + kc * 32);
#pragma unroll
        for (int i = 0; i < 8; ++i) wr[i] = wp[i];
#pragma unroll
        for (int ii = 0; ii < 32; ++ii) {
            const int gi = half + 2 * ii;
            const float4* pp = (const float4*)(&Z[gi * FD + kc * 32]);
            float d = 0.f;
#pragma unroll
            for (int i = 0; i < 8; ++i) {
                const float4 w4 = wr[i], p4 = pp[i];
                d += w4.x * p4.x + w4.y * p4.y + w4.z * p4.z + w4.w * p4.w;
            }
            acc[ii] += d;
        }
    }
    s1 = 0.f; s2 = 0.f;
    {
        const float bc = A2b[c];
#pragma unroll
        for (int ii = 0; ii < 32; ++ii) {
            const float a = acc[ii] + bc;
            acc[ii] = a; s1 += a; s2 += a * a;
        }
    }
    red[t] = s1; __syncthreads();
    if (t < 128) ml[c] = (red[t] + red[t + 128]) * (1.0f / NG);
    __syncthreads();
    red[t] = s2; __syncthreads();
    if (t < 128) {
        const float ms = (red[t] + red[t + 128]) * (1.0f / NG);
        const float mm = ml[c];
        il[c] = rsqrtf(ms - mm * mm + EPSV);
    }
    __syncthreads();
    {
        const float mm = ml[c], iv = il[c], gg = Ag2[c], bb = Ab2[c];
#pragma unroll
        for (int ii = 0; ii < 32; ++ii) {
            const int gi = half + 2 * ii;
            Z[gi * FD + c] = fmaxf((acc[ii] - mm) * iv * gg + bb, 0.f);
        }
    }
    __syncthreads();
    for (int i = t; i < NG * NA; i += 256) {
        const int gi = i >> 4;
        const int a = i & 15;
        const float4* wp = (const float4*)(A3w + a * FD);
        const float4* pp = (const float4*)(&Z[gi * FD]);
        float d = A3b[a];
#pragma unroll 8
        for (int k4 = 0; k4 < 32; ++k4) {
            const float4 w4 = wp[k4];
            const float4 p4 = pp[k4];
            d += w4.x * p4.x + w4.y * p4.y + w4.z * p4.z + w4.w * p4.w;
        }
        out[i] = sigf(d);
    }
}

extern "C" void kernel_launch(void* const* d_in, const int* in_sizes, int n_in,
                              void* d_out, int out_size, void* d_ws, size_t ws_size,
                              hipStream_t stream)
{
    const float* x     = (const float*)d_in[0];
    const float* ea    = (const float*)d_in[1];
    const int*   ei    = (const int*)d_in[2];
    const int*   batch = (const int*)d_in[3];
    const float* W1  = (const float*)d_in[4];
    const float* b1  = (const float*)d_in[5];
    const float* We1 = (const float*)d_in[6];
    const float* be1 = (const float*)d_in[7];
    const float* g1  = (const float*)d_in[8];
    const float* bt1 = (const float*)d_in[9];
    const float* W2  = (const float*)d_in[10];
    const float* b2  = (const float*)d_in[11];
    const float* We2 = (const float*)d_in[12];
    const float* be2 = (const float*)d_in[13];
    const float* g2  = (const float*)d_in[14];
    const float* bt2 = (const float*)d_in[15];
    const float* A1w = (const float*)d_in[16];
    const float* A1b = (const float*)d_in[17];
    const float* Ag1 = (const float*)d_in[18];
    const float* Ab1 = (const float*)d_in[19];
    const float* A2w = (const float*)d_in[20];
    const float* A2b = (const float*)d_in[21];
    const float* Ag2 = (const float*)d_in[22];
    const float* Ab2 = (const float*)d_in[23];
    const float* A3w = (const float*)d_in[24];
    const float* A3b = (const float*)d_in[25];
    float* out = (float*)d_out;

    float* ws      = (float*)d_ws;
    float* xpa     = ws;                       // [NN*FD]
    float* hpre    = ws + (long)NN * FD;       // [NN*FD]
    float* stats   = ws + 2L * NN * FD;        // 512 + NG*FD + 8 floats
    float* colsum1 = stats;
    float* colsq1  = stats + 128;
    float* colsum2 = stats + 256;
    float* colsq2  = stats + 384;
    float* pooled  = stats + 512;
    int*   ctr1    = (int*)(stats + 512 + NG * FD);
    int*   ctr2    = ctr1 + 1;
    int*   ibase   = (int*)(stats + 512 + NG * FD + 8);
    int2*  perm    = (int2*)ibase;             // [NE]
    int*   off     = ibase + 2 * NE;           // [NN+2]
    int*   cur     = off + NN + 2;             // [NN]
    int*   chunk   = cur + NN;                 // [256]

    hipMemsetAsync(off, 0, (NN + 2) * sizeof(int), stream);
    hipMemsetAsync(stats, 0, (512 + NG * FD + 8) * sizeof(float), stream);

    // CSR build (once; shared by both stages)
    count_kernel<<<NE / 256, 256, 0, stream>>>(ei, off);
    scan1_kernel<<<NCH, 256, 0, stream>>>(off, chunk);
    scan2_kernel<<<1, 256, 0, stream>>>(chunk);
    scan3_kernel<<<NCH, 256, 0, stream>>>(off, cur, chunk);
    scatter_kernel<<<NE / 256, 256, 0, stream>>>(ei, cur, perm);

    // stage 1
    edge_agg_kernel<false><<<2048, 128, 0, stream>>>(
        x, nullptr, nullptr, nullptr, nullptr, ea, off, perm, We1, be1, ctr1, xpa);
    node_kernel<<<(NN + BR - 1) / BR, 256, 0, stream>>>(xpa, W1, b1, hpre, colsum1, colsq1);

    // stage 2 (BN+relu of stage 1 fused into the gather)
    edge_agg_kernel<true><<<2048, 128, 0, stream>>>(
        hpre, colsum1, colsq1, g1, bt1, ea, off, perm, We2, be2, ctr2, xpa);
    node_kernel<<<(NN + BR - 1) / BR, 256, 0, stream>>>(xpa, W2, b2, hpre, colsum2, colsq2);

    norm_pool_kernel<<<(NN + 127) / 128, 256, 0, stream>>>(
        hpre, colsum2, colsq2, g2, bt2, batch, pooled);
    mlp_kernel<<<1, 256, 0, stream>>>(pooled, batch, A1w, A1b, Ag1, Ab1,
                                      A2w, A2b, Ag2, Ab2, A3w, A3b, out);
}

// Round 8
// 1055.897 us; speedup vs baseline: 5.2496x; 5.2496x over previous
//
#include <hip/hip_runtime.h>
#include <math.h>

#define NN 50000
#define NE 800000
#define FD 128
#define EDD 32
#define NG 64
#define NA 16
#define EPSV 1e-5f
#define NCH 196            // ceil(NN/256) chunks for the scan
#define EC 32              // edges staged per chunk per wave
#define NPW 4              // nodes per unit
#define BR 128             // node GEMM: rows per block tile
#define BK 32              // node GEMM: k panel

typedef float v2f __attribute__((ext_vector_type(2)));

__device__ __forceinline__ float sigf(float v) { return 1.0f / (1.0f + __expf(-v)); }
__device__ __forceinline__ v2f mk2(float a, float b) { v2f r; r.x = a; r.y = b; return r; }
__device__ __forceinline__ v2f pfma(v2f a, v2f b, v2f c) { return __builtin_elementwise_fma(a, b, c); }
__device__ __forceinline__ v2f pmax0(v2f a) { return __builtin_elementwise_max(a, mk2(0.f, 0.f)); }

// ============ counting sort of edges by dst (CSR build) ====================
__global__ __launch_bounds__(256) void count_kernel(const int* __restrict__ ei,
                                                    int* __restrict__ off)
{
    const int e = blockIdx.x * 256 + threadIdx.x;
    atomicAdd(&off[ei[NE + e]], 1);
}

__global__ __launch_bounds__(256) void scan1_kernel(const int* __restrict__ off,
                                                    int* __restrict__ chunk)
{
    __shared__ int red[256];
    const int i = blockIdx.x * 256 + threadIdx.x;
    red[threadIdx.x] = (i < NN) ? off[i] : 0;
    __syncthreads();
    for (int o = 128; o > 0; o >>= 1) {
        if (threadIdx.x < o) red[threadIdx.x] += red[threadIdx.x + o];
        __syncthreads();
    }
    if (threadIdx.x == 0) chunk[blockIdx.x] = red[0];
}

__global__ __launch_bounds__(256) void scan2_kernel(int* __restrict__ chunk)
{
    __shared__ int sh[256];
    const int t = threadIdx.x;
    const int v = (t < NCH) ? chunk[t] : 0;
    sh[t] = v;
    __syncthreads();
    for (int o = 1; o < 256; o <<= 1) {
        int x = (t >= o) ? sh[t - o] : 0;
        __syncthreads();
        sh[t] += x;
        __syncthreads();
    }
    if (t < NCH) chunk[t] = sh[t] - v;
}

__global__ __launch_bounds__(256) void scan3_kernel(int* __restrict__ off,
                                                    int* __restrict__ cur,
                                                    const int* __restrict__ chunk)
{
    __shared__ int sh[256];
    const int t = threadIdx.x;
    const int i = blockIdx.x * 256 + t;
    const int v = (i < NN) ? off[i] : 0;
    sh[t] = v;
    __syncthreads();
    for (int o = 1; o < 256; o <<= 1) {
        int x = (t >= o) ? sh[t - o] : 0;
        __syncthreads();
        sh[t] += x;
        __syncthreads();
    }
    const int ex = sh[t] - v + chunk[blockIdx.x];
    if (i < NN) { off[i] = ex; cur[i] = ex; }
    if (i == 0) off[NN] = NE;
}

__global__ __launch_bounds__(256) void scatter_kernel(const int* __restrict__ ei,
                                                      int* __restrict__ cur,
                                                      int2* __restrict__ perm)
{
    const int e = blockIdx.x * 256 + threadIdx.x;
    const int src = ei[e];
    const int dst = ei[NE + e];
    const int pos = atomicAdd(&cur[dst], 1);
    perm[pos] = make_int2(src, e);
}

// ============ gather edge stage: persistent waves + work stealing ==========
// Verified-clean R1 structure (inline edge body, NO lambdas in hot path —
// lambda+while demotes to scratch, proven 4x). Single change vs R1:
// unit = 4 nodes (was 8) and grid 4096 (was 2048) to lift occupancy from
// the 29% grid-cap toward the 6-wave/SIMD VGPR limit.
template<bool TR>
__global__ __launch_bounds__(128) void edge_agg_kernel(
    const float* __restrict__ xin, const float* __restrict__ cs,
    const float* __restrict__ cq, const float* __restrict__ ga,
    const float* __restrict__ bb, const float* __restrict__ eattr,
    const int* __restrict__ off, const int2* __restrict__ perm,
    const float* __restrict__ We, const float* __restrict__ be,
    int* __restrict__ ctr, float* __restrict__ xpa)
{
    __shared__ float ea_s[2][EC * EDD];   // 8 KB, per-wave private
    const int t = threadIdx.x;
    const int w = t >> 6;
    const int l = t & 63;

    // packed weights: wk[k] = {We[l][k], We[l+64][k]}
    v2f wk[EDD];
    {
        const float4* a  = (const float4*)(We + l * EDD);
        const float4* b2 = (const float4*)(We + (l + 64) * EDD);
#pragma unroll
        for (int i = 0; i < 8; ++i) {
            const float4 va = a[i], vb = b2[i];
            wk[4*i+0] = mk2(va.x, vb.x);
            wk[4*i+1] = mk2(va.y, vb.y);
            wk[4*i+2] = mk2(va.z, vb.z);
            wk[4*i+3] = mk2(va.w, vb.w);
        }
    }
    const v2f bev = mk2(be[l], be[l + 64]);
    v2f Av = mk2(1.f, 1.f), Bv = mk2(0.f, 0.f);
    if (TR) {
        const float invN = 1.0f / (float)NN;
        const float m0 = cs[l] * invN;
        const float i0 = rsqrtf(cq[l] * invN - m0 * m0 + EPSV);
        const float m1 = cs[l + 64] * invN;
        const float i1 = rsqrtf(cq[l + 64] * invN - m1 * m1 + EPSV);
        Av = mk2(i0 * ga[l], i1 * ga[l + 64]);
        Bv = mk2(bb[l] - m0 * Av.x, bb[l + 64] - m1 * Av.y);
    }
    const int p   = l & 7;
    const int jb0 = l >> 3;

    auto ldx = [&](int node) -> v2f {
        v2f v = mk2(xin[(long)node * FD + l], xin[(long)node * FD + 64 + l]);
        return TR ? pmax0(pfma(v, Av, Bv)) : v;
    };

    for (;;) {
        int u = 0;
        if (l == 0) u = atomicAdd(ctr, 1);
        u = __builtin_amdgcn_readfirstlane(u);   // wave-uniform in SGPR
        if (u >= NN / NPW) break;
        {
            const int n0 = u * NPW;
            const int o0 = off[n0];
            const int o1 = off[n0 + 1];
            const int o2 = off[n0 + 2];
            const int o3 = off[n0 + 3];
            const int o4 = off[n0 + 4];
            const v2f ni0 = ldx(n0), ni1 = ldx(n0 + 1);
            const v2f ni2 = ldx(n0 + 2), ni3 = ldx(n0 + 3);
            const int nchk = (o4 - o0 + EC - 1) / EC;

            float4 pf[4];
            auto prefetch = [&](int ch) {
                const int bse = o0 + ch * EC;
                const int nn = min(EC, o4 - bse);
#pragma unroll
                for (int r = 0; r < 4; ++r) {
                    const int jj = jb0 + 8 * r;
                    pf[r] = (jj < nn)
                        ? *(const float4*)(eattr + (long)perm[bse + jj].y * EDD + p * 4)
                        : make_float4(0.f, 0.f, 0.f, 0.f);
                }
            };

            int cur = n0;
            int nxt_end = o1;
            v2f acc = ni0;
            int eidx = o0;

            if (nchk > 0) prefetch(0);
#pragma unroll 1
            for (int ch = 0; ch < nchk; ++ch) {
                const int base = o0 + ch * EC;
                const int n = min(EC, o4 - base);
#pragma unroll
                for (int r = 0; r < 4; ++r)
                    *(float4*)(&ea_s[w][(jb0 + 8 * r) * EDD + p * 4]) = pf[r];
                if (ch + 1 < nchk) prefetch(ch + 1);

                // gather pipeline: group of 8 edges, one group in flight
                v2f cx[8];
                {
                    int s0[8];
#pragma unroll
                    for (int q = 0; q < 8; ++q) s0[q] = perm[base + q].x;
#pragma unroll
                    for (int q = 0; q < 8; ++q)
                        cx[q] = (q < n)
                            ? mk2(xin[(long)s0[q] * FD + l], xin[(long)s0[q] * FD + 64 + l])
                            : mk2(0.f, 0.f);
                }
                const int ng = (n + 7) >> 3;
#pragma unroll 1
                for (int g = 0; g < ng; ++g) {
                    v2f n2[8];
                    {
                        const int jb = g * 8 + 8;
                        int s2[8];
#pragma unroll
                        for (int q = 0; q < 8; ++q) s2[q] = perm[base + jb + q].x;
#pragma unroll
                        for (int q = 0; q < 8; ++q)
                            n2[q] = (jb + q < n)
                                ? mk2(xin[(long)s2[q] * FD + l], xin[(long)s2[q] * FD + 64 + l])
                                : mk2(0.f, 0.f);
                    }
#pragma unroll
                    for (int q = 0; q < 8; ++q) {
                        const int j = g * 8 + q;
                        if (j < n) {
                            while (eidx == nxt_end) {
                                xpa[(long)cur * FD + l]      = acc.x;
                                xpa[(long)cur * FD + 64 + l] = acc.y;
                                ++cur;
                                acc     = (cur == n0 + 1) ? ni1 : (cur == n0 + 2) ? ni2 : ni3;
                                nxt_end = (cur == n0 + 1) ? o2  : (cur == n0 + 2) ? o3  : o4;
                            }
                            const float4* ev = (const float4*)(&ea_s[w][j * EDD]);
                            v2f ma = bev, mb = mk2(0.f, 0.f);
#pragma unroll
                            for (int k = 0; k < 8; ++k) {
                                const float4 v = ev[k];
                                ma = pfma(mk2(v.x, v.x), wk[4*k+0], ma);
                                mb = pfma(mk2(v.y, v.y), wk[4*k+1], mb);
                                ma = pfma(mk2(v.z, v.z), wk[4*k+2], ma);
                                mb = pfma(mk2(v.w, v.w), wk[4*k+3], mb);
                            }
                            const v2f tx = TR ? pmax0(pfma(cx[q], Av, Bv)) : cx[q];
                            acc += pmax0(ma + mb + tx);
                            ++eidx;
                        }
                    }
#pragma unroll
                    for (int q = 0; q < 8; ++q) cx[q] = n2[q];
                }
            }
            for (;;) {
                xpa[(long)cur * FD + l]      = acc.x;
                xpa[(long)cur * FD + 64 + l] = acc.y;
                if (cur == n0 + 3) break;
                ++cur;
                acc = (cur == n0 + 1) ? ni1 : (cur == n0 + 2) ? ni2 : ni3;
            }
        }
    }
}

// ============ node GEMM: hpre = xpa @ W^T + b, fused BN column stats =======
__global__ __launch_bounds__(256) void node_kernel(
    const float* __restrict__ xpa, const float* __restrict__ W,
    const float* __restrict__ b, float* __restrict__ hpre,
    float* __restrict__ colsum, float* __restrict__ colsq)
{
    __shared__ float As[BK][BR + 4];
    __shared__ float Ws[BK][128 + 4];
    const int t = threadIdx.x;
    const int cg = t & 15;        // col group -> cols c0..c0+7
    const int rg = t >> 4;        // row group -> rows rg*8..+7
    const int c0 = cg * 8;
    const int r0 = blockIdx.x * BR;
    const int sr = t >> 1;        // staging row/col 0..127
    const int kq = (t & 1) * 16;  // staging k offset

    float acc[8][8];
#pragma unroll
    for (int j = 0; j < 8; ++j)
#pragma unroll
        for (int i = 0; i < 8; ++i) acc[j][i] = 0.f;

#pragma unroll 1
    for (int pn = 0; pn < 4; ++pn) {
        const int k0 = pn * BK;
        __syncthreads();
        {
            const int rG = r0 + sr;
            const float* ap = xpa + (long)rG * FD + k0 + kq;
#pragma unroll
            for (int i = 0; i < 4; ++i) {
                const float4 v = (rG < NN) ? *(const float4*)(ap + i * 4)
                                           : make_float4(0.f, 0.f, 0.f, 0.f);
                As[kq + i * 4 + 0][sr] = v.x;
                As[kq + i * 4 + 1][sr] = v.y;
                As[kq + i * 4 + 2][sr] = v.z;
                As[kq + i * 4 + 3][sr] = v.w;
            }
        }
        {
            const float* wp2 = W + sr * FD + k0 + kq;
#pragma unroll
            for (int i = 0; i < 4; ++i) {
                const float4 v = *(const float4*)(wp2 + i * 4);
                Ws[kq + i * 4 + 0][sr] = v.x;
                Ws[kq + i * 4 + 1][sr] = v.y;
                Ws[kq + i * 4 + 2][sr] = v.z;
                Ws[kq + i * 4 + 3][sr] = v.w;
            }
        }
        __syncthreads();
#pragma unroll
        for (int k = 0; k < BK; ++k) {
            const float4 a0 = *(const float4*)&As[k][rg * 8];
            const float4 a1 = *(const float4*)&As[k][rg * 8 + 4];
            const float4 w0 = *(const float4*)&Ws[k][c0];
            const float4 w1 = *(const float4*)&Ws[k][c0 + 4];
            const float av[8] = {a0.x,a0.y,a0.z,a0.w,a1.x,a1.y,a1.z,a1.w};
            const float wv[8] = {w0.x,w0.y,w0.z,w0.w,w1.x,w1.y,w1.z,w1.w};
#pragma unroll
            for (int j = 0; j < 8; ++j)
#pragma unroll
                for (int i = 0; i < 8; ++i)
                    acc[j][i] = fmaf(av[j], wv[i], acc[j][i]);
        }
    }
    float bv[8];
#pragma unroll
    for (int i = 0; i < 8; ++i) bv[i] = b[c0 + i];
    float s1[8], s2[8];
#pragma unroll
    for (int i = 0; i < 8; ++i) { s1[i] = 0.f; s2[i] = 0.f; }
#pragma unroll
    for (int j = 0; j < 8; ++j) {
        const int r = r0 + rg * 8 + j;
        if (r < NN) {
            float v[8];
#pragma unroll
            for (int i = 0; i < 8; ++i) {
                v[i] = acc[j][i] + bv[i];
                s1[i] += v[i];
                s2[i] += v[i] * v[i];
            }
            *(float4*)(hpre + (long)r * FD + c0)     = make_float4(v[0],v[1],v[2],v[3]);
            *(float4*)(hpre + (long)r * FD + c0 + 4) = make_float4(v[4],v[5],v[6],v[7]);
        }
    }
    __syncthreads();
#pragma unroll
    for (int i = 0; i < 8; ++i) As[rg][c0 + i] = s1[i];
    __syncthreads();
    if (t < 128) {
        float s = 0.f;
#pragma unroll
        for (int g = 0; g < 16; ++g) s += As[g][t];
        atomicAdd(&colsum[t], s);
    }
    __syncthreads();
#pragma unroll
    for (int i = 0; i < 8; ++i) As[rg][c0 + i] = s2[i];
    __syncthreads();
    if (t < 128) {
        float s = 0.f;
#pragma unroll
        for (int g = 0; g < 16; ++g) s += As[g][t];
        atomicAdd(&colsq[t], s);
    }
}

// ============ BN + relu + sigmoid + per-graph pooled sums (layer 2) ========
__global__ __launch_bounds__(256) void norm_pool_kernel(
    const float* __restrict__ hpre, const float* __restrict__ cs,
    const float* __restrict__ cq, const float* __restrict__ ga,
    const float* __restrict__ bb, const int* __restrict__ batch,
    float* __restrict__ pooled)
{
    __shared__ float pl[NG * FD];
    const int t = threadIdx.x;
    const int c = t & 127;
    const int half = t >> 7;
    const int r0 = blockIdx.x * 128;
    const int rend = min(r0 + 128, NN);
    const int gmin = batch[r0];
    const int gmax = batch[rend - 1];
    const int span = gmax - gmin + 1;
    for (int i = t; i < span * FD; i += 256) pl[i] = 0.f;
    __syncthreads();
    const float invN = 1.0f / (float)NN;
    const float m = cs[c] * invN;
    const float iv = rsqrtf(cq[c] * invN - m * m + EPSV);
    const float gg = ga[c];
    const float bt = bb[c];
    for (int ir = half; ir < 128; ir += 2) {
        const int r = r0 + ir;
        if (r >= rend) break;
        float v = (hpre[(long)r * FD + c] - m) * iv * gg + bt;
        v = sigf(fmaxf(v, 0.f));
        atomicAdd(&pl[(batch[r] - gmin) * FD + c], v);
    }
    __syncthreads();
    for (int i = t; i < span * FD; i += 256) atomicAdd(&pooled[gmin * FD + i], pl[i]);
}

__device__ __forceinline__ int lbound(const int* __restrict__ a, int n, int v)
{
    int lo = 0, hi = n;
    while (lo < hi) { const int mid = (lo + hi) >> 1; if (a[mid] < v) lo = mid + 1; else hi = mid; }
    return lo;
}

// ============ action MLP head, single block ================================
__global__ __launch_bounds__(256) void mlp_kernel(
    const float* __restrict__ pooled, const int* __restrict__ batch,
    const float* __restrict__ A1w, const float* __restrict__ A1b,
    const float* __restrict__ Ag1, const float* __restrict__ Ab1,
    const float* __restrict__ A2w, const float* __restrict__ A2b,
    const float* __restrict__ Ag2, const float* __restrict__ Ab2,
    const float* __restrict__ A3w, const float* __restrict__ A3b,
    float* __restrict__ out)
{
    __shared__ float Z[NG * FD];
    __shared__ float red[256];
    __shared__ float ml[128], il[128];
    __shared__ float cr[NG];
    const int t = threadIdx.x;
    const int c = t & 127;
    const int half = t >> 7;
    if (t < NG) {
        const int lo = lbound(batch, NN, t);
        const int hi = lbound(batch, NN, t + 1);
        cr[t] = 1.0f / fmaxf((float)(hi - lo), 1.0f);
    }
    float acc[32];
#pragma unroll
    for (int ii = 0; ii < 32; ++ii) acc[ii] = 0.f;
#pragma unroll 1
    for (int kc = 0; kc < 4; ++kc) {
        float4 wr[8];
        const float4* wp = (const float4*)(A1w + c * FD + kc * 32);
#pragma unroll
        for (int i = 0; i < 8; ++i) wr[i] = wp[i];
#pragma unroll
        for (int ii = 0; ii < 32; ++ii) {
            const int gi = half + 2 * ii;
            const float4* pp = (const float4*)(pooled + gi * FD + kc * 32);
            float d = 0.f;
#pragma unroll
            for (int i = 0; i < 8; ++i) {
                const float4 w4 = wr[i], p4 = pp[i];
                d += w4.x * p4.x + w4.y * p4.y + w4.z * p4.z + w4.w * p4.w;
            }
            acc[ii] += d;
        }
    }
    __syncthreads();
    float s1 = 0.f, s2 = 0.f;
    {
        const float bc = A1b[c];
#pragma unroll
        for (int ii = 0; ii < 32; ++ii) {
            const int gi = half + 2 * ii;
            const float a = fmaf(acc[ii], cr[gi], bc);
            acc[ii] = a; s1 += a; s2 += a * a;
        }
    }
    red[t] = s1; __syncthreads();
    if (t < 128) ml[c] = (red[t] + red[t + 128]) * (1.0f / NG);
    __syncthreads();
    red[t] = s2; __syncthreads();
    if (t < 128) {
        const float ms = (red[t] + red[t + 128]) * (1.0f / NG);
        const float mm = ml[c];
        il[c] = rsqrtf(ms - mm * mm + EPSV);
    }
    __syncthreads();
    {
        const float mm = ml[c], iv = il[c], gg = Ag1[c], bb = Ab1[c];
#pragma unroll
        for (int ii = 0; ii < 32; ++ii) {
            const int gi = half + 2 * ii;
            Z[gi * FD + c] = fmaxf((acc[ii] - mm) * iv * gg + bb, 0.f);
        }
    }
    __syncthreads();
#pragma unroll
    for (int ii = 0; ii < 32; ++ii) acc[ii] = 0.f;
#pragma unroll 1
    for (int kc = 0; kc < 4; ++kc) {
        float4 wr[8];
        const float4* wp = (const float4*)(A2w + c * FD + kc * 32);
#pragma unroll
        for (int i = 0; i < 8; ++i) wr[i] = wp[i];
#pragma unroll
        for (int ii = 0; ii < 32; ++ii) {
            const int gi = half + 2 * ii;
            const float4* pp = (const float4*)(&Z[gi * FD + kc * 32]);
            float d = 0.f;
#pragma unroll
            for (int i = 0; i < 8; ++i) {
                const float4 w4 = wr[i], p4 = pp[i];
                d += w4.x * p4.x + w4.y * p4.y + w4.z * p4.z + w4.w * p4.w;
            }
            acc[ii] += d;
        }
    }
    s1 = 0.f; s2 = 0.f;
    {
        const float bc = A2b[c];
#pragma unroll
        for (int ii = 0; ii < 32; ++ii) {
            const float a = acc[ii] + bc;
            acc[ii] = a; s1 += a; s2 += a * a;
        }
    }
    red[t] = s1; __syncthreads();
    if (t < 128) ml[c] = (red[t] + red[t + 128]) * (1.0f / NG);
    __syncthreads();
    red[t] = s2; __syncthreads();
    if (t < 128) {
        const float ms = (red[t] + red[t + 128]) * (1.0f / NG);
        const float mm = ml[c];
        il[c] = rsqrtf(ms - mm * mm + EPSV);
    }
    __syncthreads();
    {
        const float mm = ml[c], iv = il[c], gg = Ag2[c], bb = Ab2[c];
#pragma unroll
        for (int ii = 0; ii < 32; ++ii) {
            const int gi = half + 2 * ii;
            Z[gi * FD + c] = fmaxf((acc[ii] - mm) * iv * gg + bb, 0.f);
        }
    }
    __syncthreads();
    for (int i = t; i < NG * NA; i += 256) {
        const int gi = i >> 4;
        const int a = i & 15;
        const float4* wp = (const float4*)(A3w + a * FD);
        const float4* pp = (const float4*)(&Z[gi * FD]);
        float d = A3b[a];
#pragma unroll 8
        for (int k4 = 0; k4 < 32; ++k4) {
            const float4 w4 = wp[k4];
            const float4 p4 = pp[k4];
            d += w4.x * p4.x + w4.y * p4.y + w4.z * p4.z + w4.w * p4.w;
        }
        out[i] = sigf(d);
    }
}

extern "C" void kernel_launch(void* const* d_in, const int* in_sizes, int n_in,
                              void* d_out, int out_size, void* d_ws, size_t ws_size,
                              hipStream_t stream)
{
    const float* x     = (const float*)d_in[0];
    const float* ea    = (const float*)d_in[1];
    const int*   ei    = (const int*)d_in[2];
    const int*   batch = (const int*)d_in[3];
    const float* W1  = (const float*)d_in[4];
    const float* b1  = (const float*)d_in[5];
    const float* We1 = (const float*)d_in[6];
    const float* be1 = (const float*)d_in[7];
    const float* g1  = (const float*)d_in[8];
    const float* bt1 = (const float*)d_in[9];
    const float* W2  = (const float*)d_in[10];
    const float* b2  = (const float*)d_in[11];
    const float* We2 = (const float*)d_in[12];
    const float* be2 = (const float*)d_in[13];
    const float* g2  = (const float*)d_in[14];
    const float* bt2 = (const float*)d_in[15];
    const float* A1w = (const float*)d_in[16];
    const float* A1b = (const float*)d_in[17];
    const float* Ag1 = (const float*)d_in[18];
    const float* Ab1 = (const float*)d_in[19];
    const float* A2w = (const float*)d_in[20];
    const float* A2b = (const float*)d_in[21];
    const float* Ag2 = (const float*)d_in[22];
    const float* Ab2 = (const float*)d_in[23];
    const float* A3w = (const float*)d_in[24];
    const float* A3b = (const float*)d_in[25];
    float* out = (float*)d_out;

    float* ws      = (float*)d_ws;
    float* xpa     = ws;                       // [NN*FD]
    float* hpre    = ws + (long)NN * FD;       // [NN*FD]
    float* stats   = ws + 2L * NN * FD;        // 512 + NG*FD + 8 floats
    float* colsum1 = stats;
    float* colsq1  = stats + 128;
    float* colsum2 = stats + 256;
    float* colsq2  = stats + 384;
    float* pooled  = stats + 512;
    int*   ctr1    = (int*)(stats + 512 + NG * FD);
    int*   ctr2    = ctr1 + 1;
    int*   ibase   = (int*)(stats + 512 + NG * FD + 8);
    int2*  perm    = (int2*)ibase;             // [NE]
    int*   off     = ibase + 2 * NE;           // [NN+2]
    int*   cur     = off + NN + 2;             // [NN]
    int*   chunk   = cur + NN;                 // [256]

    hipMemsetAsync(off, 0, (NN + 2) * sizeof(int), stream);
    hipMemsetAsync(stats, 0, (512 + NG * FD + 8) * sizeof(float), stream);

    // CSR build (once; shared by both stages)
    count_kernel<<<NE / 256, 256, 0, stream>>>(ei, off);
    scan1_kernel<<<NCH, 256, 0, stream>>>(off, chunk);
    scan2_kernel<<<1, 256, 0, stream>>>(chunk);
    scan3_kernel<<<NCH, 256, 0, stream>>>(off, cur, chunk);
    scatter_kernel<<<NE / 256, 256, 0, stream>>>(ei, cur, perm);

    // stage 1
    edge_agg_kernel<false><<<4096, 128, 0, stream>>>(
        x, nullptr, nullptr, nullptr, nullptr, ea, off, perm, We1, be1, ctr1, xpa);
    node_kernel<<<(NN + BR - 1) / BR, 256, 0, stream>>>(xpa, W1, b1, hpre, colsum1, colsq1);

    // stage 2 (BN+relu of stage 1 fused into the gather)
    edge_agg_kernel<true><<<4096, 128, 0, stream>>>(
        hpre, colsum1, colsq1, g1, bt1, ea, off, perm, We2, be2, ctr2, xpa);
    node_kernel<<<(NN + BR - 1) / BR, 256, 0, stream>>>(xpa, W2, b2, hpre, colsum2, colsq2);

    norm_pool_kernel<<<(NN + 127) / 128, 256, 0, stream>>>(
        hpre, colsum2, colsq2, g2, bt2, batch, pooled);
    mlp_kernel<<<1, 256, 0, stream>>>(pooled, batch, A1w, A1b, Ag1, Ab1,
                                      A2w, A2b, Ag2, Ab2, A3w, A3b, out);
}

// Round 9
// 870.945 us; speedup vs baseline: 6.3643x; 1.2124x over previous
//
#include <hip/hip_runtime.h>
#include <math.h>

#define NN 50000
#define NE 800000
#define FD 128
#define EDD 32
#define NG 64
#define NA 16
#define EPSV 1e-5f
#define NCH 196            // ceil(NN/256) chunks for the scan
#define EC 8               // edges per chunk (one 8-edge readlane group)
#define NPW 4              // nodes per body
#define BR 128             // node GEMM: rows per block tile
#define BK 32              // node GEMM: k panel

typedef float v2f __attribute__((ext_vector_type(2)));

__device__ __forceinline__ float sigf(float v) { return 1.0f / (1.0f + __expf(-v)); }
__device__ __forceinline__ v2f mk2(float a, float b) { v2f r; r.x = a; r.y = b; return r; }
__device__ __forceinline__ v2f pfma(v2f a, v2f b, v2f c) { return __builtin_elementwise_fma(a, b, c); }
__device__ __forceinline__ v2f pmax0(v2f a) { return __builtin_elementwise_max(a, mk2(0.f, 0.f)); }
// broadcast one float from a (compile-time) lane to the whole wave via SGPR
__device__ __forceinline__ float rlane(float v, int lane) {
    return __int_as_float(__builtin_amdgcn_readlane(__float_as_int(v), lane));
}

// ============ counting sort of edges by dst (CSR build) ====================
__global__ __launch_bounds__(256) void count_kernel(const int* __restrict__ ei,
                                                    int* __restrict__ off)
{
    const int e = blockIdx.x * 256 + threadIdx.x;
    atomicAdd(&off[ei[NE + e]], 1);
}

__global__ __launch_bounds__(256) void scan1_kernel(const int* __restrict__ off,
                                                    int* __restrict__ chunk)
{
    __shared__ int red[256];
    const int i = blockIdx.x * 256 + threadIdx.x;
    red[threadIdx.x] = (i < NN) ? off[i] : 0;
    __syncthreads();
    for (int o = 128; o > 0; o >>= 1) {
        if (threadIdx.x < o) red[threadIdx.x] += red[threadIdx.x + o];
        __syncthreads();
    }
    if (threadIdx.x == 0) chunk[blockIdx.x] = red[0];
}

__global__ __launch_bounds__(256) void scan2_kernel(int* __restrict__ chunk)
{
    __shared__ int sh[256];
    const int t = threadIdx.x;
    const int v = (t < NCH) ? chunk[t] : 0;
    sh[t] = v;
    __syncthreads();
    for (int o = 1; o < 256; o <<= 1) {
        int x = (t >= o) ? sh[t - o] : 0;
        __syncthreads();
        sh[t] += x;
        __syncthreads();
    }
    if (t < NCH) chunk[t] = sh[t] - v;
}

__global__ __launch_bounds__(256) void scan3_kernel(int* __restrict__ off,
                                                    int* __restrict__ cur,
                                                    const int* __restrict__ chunk)
{
    __shared__ int sh[256];
    const int t = threadIdx.x;
    const int i = blockIdx.x * 256 + t;
    const int v = (i < NN) ? off[i] : 0;
    sh[t] = v;
    __syncthreads();
    for (int o = 1; o < 256; o <<= 1) {
        int x = (t >= o) ? sh[t - o] : 0;
        __syncthreads();
        sh[t] += x;
        __syncthreads();
    }
    const int ex = sh[t] - v + chunk[blockIdx.x];
    if (i < NN) { off[i] = ex; cur[i] = ex; }
    if (i == 0) off[NN] = NE;
}

__global__ __launch_bounds__(256) void scatter_kernel(const int* __restrict__ ei,
                                                      int* __restrict__ cur,
                                                      int2* __restrict__ perm)
{
    const int e = blockIdx.x * 256 + threadIdx.x;
    const int src = ei[e];
    const int dst = ei[NE + e];
    const int pos = atomicAdd(&cur[dst], 1);
    perm[pos] = make_int2(src, e);
}

// ============ gather edge stage: persistent waves + work stealing ==========
// ZERO LDS. Edge attrs ride in registers: lane 8q+p holds attrs [4p,4p+4)
// of chunk-edge q (one float4 'pf'); per-edge the 32 attrs broadcast to the
// wave via v_readlane (literal lanes, SGPR result, no memory counters, no
// DS pipe). Inline edge body, named pf/nf, R1-proven cx[4]/nx[4] gather
// pipeline with full unrolls — shapes verified demotion-free.
template<bool TR>
__global__ __launch_bounds__(128) void edge_agg_kernel(
    const float* __restrict__ xin, const float* __restrict__ cs,
    const float* __restrict__ cq, const float* __restrict__ ga,
    const float* __restrict__ bb, const float* __restrict__ eattr,
    const int* __restrict__ off, const int2* __restrict__ perm,
    const float* __restrict__ We, const float* __restrict__ be,
    int* __restrict__ ctr, float* __restrict__ xpa)
{
    const int t = threadIdx.x;
    const int l = t & 63;

    // packed weights: wk[k] = {We[l][k], We[l+64][k]}
    v2f wk[EDD];
    {
        const float4* a  = (const float4*)(We + l * EDD);
        const float4* b2 = (const float4*)(We + (l + 64) * EDD);
#pragma unroll
        for (int i = 0; i < 8; ++i) {
            const float4 va = a[i], vb = b2[i];
            wk[4*i+0] = mk2(va.x, vb.x);
            wk[4*i+1] = mk2(va.y, vb.y);
            wk[4*i+2] = mk2(va.z, vb.z);
            wk[4*i+3] = mk2(va.w, vb.w);
        }
    }
    const v2f bev = mk2(be[l], be[l + 64]);
    v2f Av = mk2(1.f, 1.f), Bv = mk2(0.f, 0.f);
    if (TR) {
        const float invN = 1.0f / (float)NN;
        const float m0 = cs[l] * invN;
        const float i0 = rsqrtf(cq[l] * invN - m0 * m0 + EPSV);
        const float m1 = cs[l + 64] * invN;
        const float i1 = rsqrtf(cq[l + 64] * invN - m1 * m1 + EPSV);
        Av = mk2(i0 * ga[l], i1 * ga[l + 64]);
        Bv = mk2(bb[l] - m0 * Av.x, bb[l + 64] - m1 * Av.y);
    }
    const int p   = l & 7;     // attr sub-block this lane stages
    const int jb0 = l >> 3;    // chunk-edge this lane stages

    auto ldx = [&](int node) -> v2f {
        v2f v = mk2(xin[(long)node * FD + l], xin[(long)node * FD + 64 + l]);
        return TR ? pmax0(pfma(v, Av, Bv)) : v;
    };

    for (;;) {
        int u = 0;
        if (l == 0) u = atomicAdd(ctr, 1);
        u = __builtin_amdgcn_readfirstlane(u);   // wave-uniform in SGPR
        if (u >= NN / 8) break;
#pragma unroll 1
        for (int rep = 0; rep < 2; ++rep) {
            const int n0 = u * 8 + rep * NPW;
            const int o0 = off[n0];
            const int o1 = off[n0 + 1];
            const int o2 = off[n0 + 2];
            const int o3 = off[n0 + 3];
            const int o4 = off[n0 + 4];
            const v2f ni0 = ldx(n0), ni1 = ldx(n0 + 1);
            const v2f ni2 = ldx(n0 + 2), ni3 = ldx(n0 + 3);
            const int nchk = (o4 - o0 + EC - 1) / EC;

            int cur = n0;
            int nxt_end = o1;
            v2f acc = ni0;
            int eidx = o0;

            float4 pf = make_float4(0.f, 0.f, 0.f, 0.f);
            v2f cx[4];
            if (nchk > 0) {
                const int nn0 = min(EC, o4 - o0);
                pf = (jb0 < nn0)
                    ? *(const float4*)(eattr + (long)perm[o0 + jb0].y * EDD + p * 4)
                    : make_float4(0.f, 0.f, 0.f, 0.f);
#pragma unroll
                for (int q = 0; q < 4; ++q) {
                    if (q < nn0) {
                        const int s = perm[o0 + q].x;
                        cx[q] = mk2(xin[(long)s * FD + l], xin[(long)s * FD + 64 + l]);
                    } else cx[q] = mk2(0.f, 0.f);
                }
            }

#pragma unroll 1
            for (int ch = 0; ch < nchk; ++ch) {
                const int base = o0 + ch * EC;
                const int n = min(EC, o4 - base);
                const int nn1 = (ch + 1 < nchk) ? min(EC, o4 - (base + EC)) : 0;

                // 1. prefetch next chunk's attrs (used a full chunk later)
                const float4 nf = (jb0 < nn1)
                    ? *(const float4*)(eattr + (long)perm[base + EC + jb0].y * EDD + p * 4)
                    : make_float4(0.f, 0.f, 0.f, 0.f);

                // 2. issue gathers for edges 4..7 (used after computing 0..3)
                v2f nx[4];
#pragma unroll
                for (int q = 0; q < 4; ++q) {
                    if (4 + q < n) {
                        const int s = perm[base + 4 + q].x;
                        nx[q] = mk2(xin[(long)s * FD + l], xin[(long)s * FD + 64 + l]);
                    } else nx[q] = mk2(0.f, 0.f);
                }

                // 3. compute edges 0..3
#pragma unroll
                for (int q = 0; q < 4; ++q) {
                    if (q < n) {
                        while (eidx == nxt_end) {
                            xpa[(long)cur * FD + l]      = acc.x;
                            xpa[(long)cur * FD + 64 + l] = acc.y;
                            ++cur;
                            acc     = (cur == n0 + 1) ? ni1 : (cur == n0 + 2) ? ni2 : ni3;
                            nxt_end = (cur == n0 + 1) ? o2  : (cur == n0 + 2) ? o3  : o4;
                        }
                        v2f ma = bev, mb = mk2(0.f, 0.f);
#pragma unroll
                        for (int pp = 0; pp < 8; ++pp) {
                            const float a0 = rlane(pf.x, 8 * q + pp);
                            const float a1 = rlane(pf.y, 8 * q + pp);
                            const float a2 = rlane(pf.z, 8 * q + pp);
                            const float a3 = rlane(pf.w, 8 * q + pp);
                            ma = pfma(mk2(a0, a0), wk[4*pp+0], ma);
                            mb = pfma(mk2(a1, a1), wk[4*pp+1], mb);
                            ma = pfma(mk2(a2, a2), wk[4*pp+2], ma);
                            mb = pfma(mk2(a3, a3), wk[4*pp+3], mb);
                        }
                        const v2f tx = TR ? pmax0(pfma(cx[q], Av, Bv)) : cx[q];
                        acc += pmax0(ma + mb + tx);
                        ++eidx;
                    }
                }

                // 4. issue gathers for next chunk's edges 0..3
#pragma unroll
                for (int q = 0; q < 4; ++q) {
                    if (q < nn1) {
                        const int s = perm[base + EC + q].x;
                        cx[q] = mk2(xin[(long)s * FD + l], xin[(long)s * FD + 64 + l]);
                    } else cx[q] = mk2(0.f, 0.f);
                }

                // 5. compute edges 4..7
#pragma unroll
                for (int q = 4; q < 8; ++q) {
                    if (q < n) {
                        while (eidx == nxt_end) {
                            xpa[(long)cur * FD + l]      = acc.x;
                            xpa[(long)cur * FD + 64 + l] = acc.y;
                            ++cur;
                            acc     = (cur == n0 + 1) ? ni1 : (cur == n0 + 2) ? ni2 : ni3;
                            nxt_end = (cur == n0 + 1) ? o2  : (cur == n0 + 2) ? o3  : o4;
                        }
                        v2f ma = bev, mb = mk2(0.f, 0.f);
#pragma unroll
                        for (int pp = 0; pp < 8; ++pp) {
                            const float a0 = rlane(pf.x, 8 * q + pp);
                            const float a1 = rlane(pf.y, 8 * q + pp);
                            const float a2 = rlane(pf.z, 8 * q + pp);
                            const float a3 = rlane(pf.w, 8 * q + pp);
                            ma = pfma(mk2(a0, a0), wk[4*pp+0], ma);
                            mb = pfma(mk2(a1, a1), wk[4*pp+1], mb);
                            ma = pfma(mk2(a2, a2), wk[4*pp+2], ma);
                            mb = pfma(mk2(a3, a3), wk[4*pp+3], mb);
                        }
                        const v2f tx = TR ? pmax0(pfma(nx[q - 4], Av, Bv)) : nx[q - 4];
                        acc += pmax0(ma + mb + tx);
                        ++eidx;
                    }
                }

                pf = nf;
            }
            for (;;) {
                xpa[(long)cur * FD + l]      = acc.x;
                xpa[(long)cur * FD + 64 + l] = acc.y;
                if (cur == n0 + 3) break;
                ++cur;
                acc = (cur == n0 + 1) ? ni1 : (cur == n0 + 2) ? ni2 : ni3;
            }
        }
    }
}

// ============ node GEMM: hpre = xpa @ W^T + b, fused BN column stats =======
__global__ __launch_bounds__(256) void node_kernel(
    const float* __restrict__ xpa, const float* __restrict__ W,
    const float* __restrict__ b, float* __restrict__ hpre,
    float* __restrict__ colsum, float* __restrict__ colsq)
{
    __shared__ float As[BK][BR + 4];
    __shared__ float Ws[BK][128 + 4];
    const int t = threadIdx.x;
    const int cg = t & 15;        // col group -> cols c0..c0+7
    const int rg = t >> 4;        // row group -> rows rg*8..+7
    const int c0 = cg * 8;
    const int r0 = blockIdx.x * BR;
    const int sr = t >> 1;        // staging row/col 0..127
    const int kq = (t & 1) * 16;  // staging k offset

    float acc[8][8];
#pragma unroll
    for (int j = 0; j < 8; ++j)
#pragma unroll
        for (int i = 0; i < 8; ++i) acc[j][i] = 0.f;

#pragma unroll 1
    for (int pn = 0; pn < 4; ++pn) {
        const int k0 = pn * BK;
        __syncthreads();
        {
            const int rG = r0 + sr;
            const float* ap = xpa + (long)rG * FD + k0 + kq;
#pragma unroll
            for (int i = 0; i < 4; ++i) {
                const float4 v = (rG < NN) ? *(const float4*)(ap + i * 4)
                                           : make_float4(0.f, 0.f, 0.f, 0.f);
                As[kq + i * 4 + 0][sr] = v.x;
                As[kq + i * 4 + 1][sr] = v.y;
                As[kq + i * 4 + 2][sr] = v.z;
                As[kq + i * 4 + 3][sr] = v.w;
            }
        }
        {
            const float* wp2 = W + sr * FD + k0 + kq;
#pragma unroll
            for (int i = 0; i < 4; ++i) {
                const float4 v = *(const float4*)(wp2 + i * 4);
                Ws[kq + i * 4 + 0][sr] = v.x;
                Ws[kq + i * 4 + 1][sr] = v.y;
                Ws[kq + i * 4 + 2][sr] = v.z;
                Ws[kq + i * 4 + 3][sr] = v.w;
            }
        }
        __syncthreads();
#pragma unroll
        for (int k = 0; k < BK; ++k) {
            const float4 a0 = *(const float4*)&As[k][rg * 8];
            const float4 a1 = *(const float4*)&As[k][rg * 8 + 4];
            const float4 w0 = *(const float4*)&Ws[k][c0];
            const float4 w1 = *(const float4*)&Ws[k][c0 + 4];
            const float av[8] = {a0.x,a0.y,a0.z,a0.w,a1.x,a1.y,a1.z,a1.w};
            const float wv[8] = {w0.x,w0.y,w0.z,w0.w,w1.x,w1.y,w1.z,w1.w};
#pragma unroll
            for (int j = 0; j < 8; ++j)
#pragma unroll
                for (int i = 0; i < 8; ++i)
                    acc[j][i] = fmaf(av[j], wv[i], acc[j][i]);
        }
    }
    float bv[8];
#pragma unroll
    for (int i = 0; i < 8; ++i) bv[i] = b[c0 + i];
    float s1[8], s2[8];
#pragma unroll
    for (int i = 0; i < 8; ++i) { s1[i] = 0.f; s2[i] = 0.f; }
#pragma unroll
    for (int j = 0; j < 8; ++j) {
        const int r = r0 + rg * 8 + j;
        if (r < NN) {
            float v[8];
#pragma unroll
            for (int i = 0; i < 8; ++i) {
                v[i] = acc[j][i] + bv[i];
                s1[i] += v[i];
                s2[i] += v[i] * v[i];
            }
            *(float4*)(hpre + (long)r * FD + c0)     = make_float4(v[0],v[1],v[2],v[3]);
            *(float4*)(hpre + (long)r * FD + c0 + 4) = make_float4(v[4],v[5],v[6],v[7]);
        }
    }
    __syncthreads();
#pragma unroll
    for (int i = 0; i < 8; ++i) As[rg][c0 + i] = s1[i];
    __syncthreads();
    if (t < 128) {
        float s = 0.f;
#pragma unroll
        for (int g = 0; g < 16; ++g) s += As[g][t];
        atomicAdd(&colsum[t], s);
    }
    __syncthreads();
#pragma unroll
    for (int i = 0; i < 8; ++i) As[rg][c0 + i] = s2[i];
    __syncthreads();
    if (t < 128) {
        float s = 0.f;
#pragma unroll
        for (int g = 0; g < 16; ++g) s += As[g][t];
        atomicAdd(&colsq[t], s);
    }
}

// ============ BN + relu + sigmoid + per-graph pooled sums (layer 2) ========
__global__ __launch_bounds__(256) void norm_pool_kernel(
    const float* __restrict__ hpre, const float* __restrict__ cs,
    const float* __restrict__ cq, const float* __restrict__ ga,
    const float* __restrict__ bb, const int* __restrict__ batch,
    float* __restrict__ pooled)
{
    __shared__ float pl[NG * FD];
    const int t = threadIdx.x;
    const int c = t & 127;
    const int half = t >> 7;
    const int r0 = blockIdx.x * 128;
    const int rend = min(r0 + 128, NN);
    const int gmin = batch[r0];
    const int gmax = batch[rend - 1];
    const int span = gmax - gmin + 1;
    for (int i = t; i < span * FD; i += 256) pl[i] = 0.f;
    __syncthreads();
    const float invN = 1.0f / (float)NN;
    const float m = cs[c] * invN;
    const float iv = rsqrtf(cq[c] * invN - m * m + EPSV);
    const float gg = ga[c];
    const float bt = bb[c];
    for (int ir = half; ir < 128; ir += 2) {
        const int r = r0 + ir;
        if (r >= rend) break;
        float v = (hpre[(long)r * FD + c] - m) * iv * gg + bt;
        v = sigf(fmaxf(v, 0.f));
        atomicAdd(&pl[(batch[r] - gmin) * FD + c], v);
    }
    __syncthreads();
    for (int i = t; i < span * FD; i += 256) atomicAdd(&pooled[gmin * FD + i], pl[i]);
}

__device__ __forceinline__ int lbound(const int* __restrict__ a, int n, int v)
{
    int lo = 0, hi = n;
    while (lo < hi) { const int mid = (lo + hi) >> 1; if (a[mid] < v) lo = mid + 1; else hi = mid; }
    return lo;
}

// ============ action MLP head, single block ================================
__global__ __launch_bounds__(256) void mlp_kernel(
    const float* __restrict__ pooled, const int* __restrict__ batch,
    const float* __restrict__ A1w, const float* __restrict__ A1b,
    const float* __restrict__ Ag1, const float* __restrict__ Ab1,
    const float* __restrict__ A2w, const float* __restrict__ A2b,
    const float* __restrict__ Ag2, const float* __restrict__ Ab2,
    const float* __restrict__ A3w, const float* __restrict__ A3b,
    float* __restrict__ out)
{
    __shared__ float Z[NG * FD];
    __shared__ float red[256];
    __shared__ float ml[128], il[128];
    __shared__ float cr[NG];
    const int t = threadIdx.x;
    const int c = t & 127;
    const int half = t >> 7;
    if (t < NG) {
        const int lo = lbound(batch, NN, t);
        const int hi = lbound(batch, NN, t + 1);
        cr[t] = 1.0f / fmaxf((float)(hi - lo), 1.0f);
    }
    float acc[32];
#pragma unroll
    for (int ii = 0; ii < 32; ++ii) acc[ii] = 0.f;
#pragma unroll 1
    for (int kc = 0; kc < 4; ++kc) {
        float4 wr[8];
        const float4* wp = (const float4*)(A1w + c * FD + kc * 32);
#pragma unroll
        for (int i = 0; i < 8; ++i) wr[i] = wp[i];
#pragma unroll
        for (int ii = 0; ii < 32; ++ii) {
            const int gi = half + 2 * ii;
            const float4* pp = (const float4*)(pooled + gi * FD + kc * 32);
            float d = 0.f;
#pragma unroll
            for (int i = 0; i < 8; ++i) {
                const float4 w4 = wr[i], p4 = pp[i];
                d += w4.x * p4.x + w4.y * p4.y + w4.z * p4.z + w4.w * p4.w;
            }
            acc[ii] += d;
        }
    }
    __syncthreads();
    float s1 = 0.f, s2 = 0.f;
    {
        const float bc = A1b[c];
#pragma unroll
        for (int ii = 0; ii < 32; ++ii) {
            const int gi = half + 2 * ii;
            const float a = fmaf(acc[ii], cr[gi], bc);
            acc[ii] = a; s1 += a; s2 += a * a;
        }
    }
    red[t] = s1; __syncthreads();
    if (t < 128) ml[c] = (red[t] + red[t + 128]) * (1.0f / NG);
    __syncthreads();
    red[t] = s2; __syncthreads();
    if (t < 128) {
        const float ms = (red[t] + red[t + 128]) * (1.0f / NG);
        const float mm = ml[c];
        il[c] = rsqrtf(ms - mm * mm + EPSV);
    }
    __syncthreads();
    {
        const float mm = ml[c], iv = il[c], gg = Ag1[c], bb = Ab1[c];
#pragma unroll
        for (int ii = 0; ii < 32; ++ii) {
            const int gi = half + 2 * ii;
            Z[gi * FD + c] = fmaxf((acc[ii] - mm) * iv * gg + bb, 0.f);
        }
    }
    __syncthreads();
#pragma unroll
    for (int ii = 0; ii < 32; ++ii) acc[ii] = 0.f;
#pragma unroll 1
    for (int kc = 0; kc < 4; ++kc) {
        float4 wr[8];
        const float4* wp = (const float4*)(A2w + c * FD + kc * 32);
#pragma unroll
        for (int i = 0; i < 8; ++i) wr[i] = wp[i];
#pragma unroll
        for (int ii = 0; ii < 32; ++ii) {
            const int gi = half + 2 * ii;
            const float4* pp = (const float4*)(&Z[gi * FD + kc * 32]);
            float d = 0.f;
#pragma unroll
            for (int i = 0; i < 8; ++i) {
                const float4 w4 = wr[i], p4 = pp[i];
                d += w4.x * p4.x + w4.y * p4.y + w4.z * p4.z + w4.w * p4.w;
            }
            acc[ii] += d;
        }
    }
    s1 = 0.f; s2 = 0.f;
    {
        const float bc = A2b[c];
#pragma unroll
        for (int ii = 0; ii < 32; ++ii) {
            const float a = acc[ii] + bc;
            acc[ii] = a; s1 += a; s2 += a * a;
        }
    }
    red[t] = s1; __syncthreads();
    if (t < 128) ml[c] = (red[t] + red[t + 128]) * (1.0f / NG);
    __syncthreads();
    red[t] = s2; __syncthreads();
    if (t < 128) {
        const float ms = (red[t] + red[t + 128]) * (1.0f / NG);
        const float mm = ml[c];
        il[c] = rsqrtf(ms - mm * mm + EPSV);
    }
    __syncthreads();
    {
        const float mm = ml[c], iv = il[c], gg = Ag2[c], bb = Ab2[c];
#pragma unroll
        for (int ii = 0; ii < 32; ++ii) {
            const int gi = half + 2 * ii;
            Z[gi * FD + c] = fmaxf((acc[ii] - mm) * iv * gg + bb, 0.f);
        }
    }
    __syncthreads();
    for (int i = t; i < NG * NA; i += 256) {
        const int gi = i >> 4;
        const int a = i & 15;
        const float4* wp = (const float4*)(A3w + a * FD);
        const float4* pp = (const float4*)(&Z[gi * FD]);
        float d = A3b[a];
#pragma unroll 8
        for (int k4 = 0; k4 < 32; ++k4) {
            const float4 w4 = wp[k4];
            const float4 p4 = pp[k4];
            d += w4.x * p4.x + w4.y * p4.y + w4.z * p4.z + w4.w * p4.w;
        }
        out[i] = sigf(d);
    }
}

extern "C" void kernel_launch(void* const* d_in, const int* in_sizes, int n_in,
                              void* d_out, int out_size, void* d_ws, size_t ws_size,
                              hipStream_t stream)
{
    const float* x     = (const float*)d_in[0];
    const float* ea    = (const float*)d_in[1];
    const int*   ei    = (const int*)d_in[2];
    const int*   batch = (const int*)d_in[3];
    const float* W1  = (const float*)d_in[4];
    const float* b1  = (const float*)d_in[5];
    const float* We1 = (const float*)d_in[6];
    const float* be1 = (const float*)d_in[7];
    const float* g1  = (const float*)d_in[8];
    const float* bt1 = (const float*)d_in[9];
    const float* W2  = (const float*)d_in[10];
    const float* b2  = (const float*)d_in[11];
    const float* We2 = (const float*)d_in[12];
    const float* be2 = (const float*)d_in[13];
    const float* g2  = (const float*)d_in[14];
    const float* bt2 = (const float*)d_in[15];
    const float* A1w = (const float*)d_in[16];
    const float* A1b = (const float*)d_in[17];
    const float* Ag1 = (const float*)d_in[18];
    const float* Ab1 = (const float*)d_in[19];
    const float* A2w = (const float*)d_in[20];
    const float* A2b = (const float*)d_in[21];
    const float* Ag2 = (const float*)d_in[22];
    const float* Ab2 = (const float*)d_in[23];
    const float* A3w = (const float*)d_in[24];
    const float* A3b = (const float*)d_in[25];
    float* out = (float*)d_out;

    float* ws      = (float*)d_ws;
    float* xpa     = ws;                       // [NN*FD]
    float* hpre    = ws + (long)NN * FD;       // [NN*FD]
    float* stats   = ws + 2L * NN * FD;        // 512 + NG*FD + 8 floats
    float* colsum1 = stats;
    float* colsq1  = stats + 128;
    float* colsum2 = stats + 256;
    float* colsq2  = stats + 384;
    float* pooled  = stats + 512;
    int*   ctr1    = (int*)(stats + 512 + NG * FD);
    int*   ctr2    = ctr1 + 1;
    int*   ibase   = (int*)(stats + 512 + NG * FD + 8);
    int2*  perm    = (int2*)ibase;             // [NE]
    int*   off     = ibase + 2 * NE;           // [NN+2]
    int*   cur     = off + NN + 2;             // [NN]
    int*   chunk   = cur + NN;                 // [256]

    hipMemsetAsync(off, 0, (NN + 2) * sizeof(int), stream);
    hipMemsetAsync(stats, 0, (512 + NG * FD + 8) * sizeof(float), stream);

    // CSR build (once; shared by both stages)
    count_kernel<<<NE / 256, 256, 0, stream>>>(ei, off);
    scan1_kernel<<<NCH, 256, 0, stream>>>(off, chunk);
    scan2_kernel<<<1, 256, 0, stream>>>(chunk);
    scan3_kernel<<<NCH, 256, 0, stream>>>(off, cur, chunk);
    scatter_kernel<<<NE / 256, 256, 0, stream>>>(ei, cur, perm);

    // stage 1
    edge_agg_kernel<false><<<2048, 128, 0, stream>>>(
        x, nullptr, nullptr, nullptr, nullptr, ea, off, perm, We1, be1, ctr1, xpa);
    node_kernel<<<(NN + BR - 1) / BR, 256, 0, stream>>>(xpa, W1, b1, hpre, colsum1, colsq1);

    // stage 2 (BN+relu of stage 1 fused into the gather)
    edge_agg_kernel<true><<<2048, 128, 0, stream>>>(
        hpre, colsum1, colsq1, g1, bt1, ea, off, perm, We2, be2, ctr2, xpa);
    node_kernel<<<(NN + BR - 1) / BR, 256, 0, stream>>>(xpa, W2, b2, hpre, colsum2, colsq2);

    norm_pool_kernel<<<(NN + 127) / 128, 256, 0, stream>>>(
        hpre, colsum2, colsq2, g2, bt2, batch, pooled);
    mlp_kernel<<<1, 256, 0, stream>>>(pooled, batch, A1w, A1b, Ag1, Ab1,
                                      A2w, A2b, Ag2, Ab2, A3w, A3b, out);
}